// Round 12
// baseline (617.032 us; speedup 1.0000x reference)
//
#include <hip/hip_runtime.h>

// Model: enc linear(37->64)+relu -> BiLSTM(H=64, T=128, B=2048) -> (degenerate
// attention == sum over T) -> 10-step decoder LSTM with constant input -> softmax(11).
//
// Exploits: attention weights are all-ones (softmax over a size-1 axis), so
// fd[b] = sum_t concat(hf,hb)[b,t,:] and att1/att2 are dead. fd@dec_wih.T is
// hoisted out of the decoder loop.
//
// R12: chunked fusion with STRICTLY PHASE-CONFINED staging. Law from R3/R5/R6/
// R11 failures: the rec loop must be clean -- no staging inside it, no
// gload_lds, no registers live across it (R11 held v[10] across the loop ->
// VGPR 128 -> 477us). Per chunk: {f4->reg->f16-LDS stage (loads consumed in
// phase), sync, e-compute, sync, 32 rec steps (R8-proven body, e from LDS)}.
// Deletes the ~40us enc kernel + 32MB efrag round-trip. LDS 108KB (1 block/CU
// by pigeonhole -- grid 256 = CU count).

typedef _Float16 f16;
typedef f16 f16x8 __attribute__((ext_vector_type(8)));
typedef f16 f16x4 __attribute__((ext_vector_type(4)));
typedef float f32x4 __attribute__((ext_vector_type(4)));

#define MFMA16(a, b, c) __builtin_amdgcn_mfma_f32_16x16x32_f16(a, b, c, 0, 0, 0)

// gate scales folded into weights: i,f,o -> -log2e ; g -> -2*log2e
// then sig = rcp(1+exp2(y)), tanh = 2*rcp(1+exp2(y)) - 1.
#define NLOG2E  -1.4426950408889634f
#define N2LOG2E -2.8853900817779268f

__device__ __forceinline__ float rcp_(float x) { return __builtin_amdgcn_rcpf(x); }
__device__ __forceinline__ float ex2_(float x) { return __builtin_amdgcn_exp2f(x); }
__device__ __forceinline__ float sigf(float x) { return 1.f / (1.f + __expf(-x)); }
__device__ __forceinline__ float tanhf_fast(float x) {
  float e = __expf(2.f * x);
  return 1.f - 2.f / (e + 1.f);
}

// ---------------- Kernel 1: fused encoder + BiLSTM + fd accumulation --------
// 512 thr / 8 waves. 4 chunks x 32 steps.
// LDS: ebunk 64KB + xst 40KB + hbuf 4KB = 108KB.
__global__ __launch_bounds__(512, 2) void bilstm_fused_k(
    const float* __restrict__ x, const float* __restrict__ w1,
    const float* __restrict__ b1,
    const float* __restrict__ wih_f, const float* __restrict__ whh_f,
    const float* __restrict__ bih_f, const float* __restrict__ bhh_f,
    const float* __restrict__ wih_b, const float* __restrict__ whh_b,
    const float* __restrict__ bih_b, const float* __restrict__ bhh_b,
    float* __restrict__ fd) {
  const int bid = blockIdx.x;
  const int dir = bid >> 7;
  const int bg = bid & 127;
  const int tid = threadIdx.x;
  const int w = tid >> 6, l = tid & 63;      // w in [0,8)
  const int rho = l & 15, c = l >> 4;
  const int gate = rho & 3, uoff = rho >> 2;

  __shared__ __align__(16) f16 ebunk[32][2][64][8]; // e frags, 32 steps (64KB)
  __shared__ __align__(16) f16 xst[32][16][40];     // x chunk (t,b,k) (40KB)
  __shared__ __align__(16) f16 hbuf[2][2][64][8];   // dbl-buffered h (4KB)

  {
    int* hz = (int*)hbuf;
    for (int i = tid; i < 1024; i += 512) hz[i] = 0;
  }

  // ---- W1 A-frags (all waves; used in e-compute each chunk) ----
  f16x8 w1a[4], w1b[4];
  f32x4 ebias[4];
#pragma unroll
  for (int m = 0; m < 4; m++) {
    const float* pw = w1 + (16 * m + rho) * 37;
    f16x8 v0, v1;
#pragma unroll
    for (int i = 0; i < 8; i++) {
      v0[i] = (f16)pw[8 * c + i];
      v1[i] = (f16)((c == 0 && i < 5) ? pw[32 + i] : 0.f);
    }
    w1a[m] = v0;
    w1b[m] = v1;
#pragma unroll
    for (int r = 0; r < 4; r++) ebias[m][r] = b1[16 * m + 4 * c + r];
  }

  // ---- recurrent weights (R8 layout: wave w owns m-tiles 2w, 2w+1) ----
  const float* wih = dir ? wih_b : wih_f;
  const float* whh = dir ? whh_b : whh_f;
  const float* bihp = dir ? bih_b : bih_f;
  const float* bhhp = dir ? bhh_b : bhh_f;
  const float sA = (gate == 2) ? N2LOG2E : NLOG2E;
  f16x8 aih[2][2], ahh[2][2];
  f32x4 bias[2];
#pragma unroll
  for (int q = 0; q < 2; q++) {
    const int m = 2 * w + q;
    const int n = gate * 64 + 4 * m + uoff;   // permuted gate-row -> W row
#pragma unroll
    for (int ks = 0; ks < 2; ks++) {
      const float* p1 = wih + n * 64 + ks * 32 + c * 8;
      const float* p2 = whh + n * 64 + ks * 32 + c * 8;
      f16x8 v1, v2;
#pragma unroll
      for (int i = 0; i < 8; i++) {
        v1[i] = (f16)(p1[i] * sA);
        v2[i] = (f16)(p2[i] * sA);
      }
      aih[q][ks] = v1;
      ahh[q][ks] = v2;
    }
    const int j = 8 * w + 4 * q + c;
#pragma unroll
    for (int r = 0; r < 4; r++) {
      const float sr = (r == 2) ? N2LOG2E : NLOG2E;
      bias[q][r] = (bihp[64 * r + j] + bhhp[64 * r + j]) * sr;
    }
  }

  const float* xbase = x + (size_t)(bg * 16) * 4736;
  float cst[2] = {0.f, 0.f};
  float hs[2] = {0.f, 0.f};

  __syncthreads();  // hbuf zeros visible before first rec phase

  for (int ch = 0; ch < 4; ch++) {
    const int pc = dir ? 3 - ch : ch;  // physical 32-t window

    // ---- stage: 4736 float4 -> regs -> f16 LDS (loads die in this phase) ----
    {
      const float* xc = xbase + pc * 1184;
#pragma unroll
      for (int it = 0; it < 10; it++) {
        const int idx = tid + it * 512;
        if (idx < 4736) {
          const int r = idx / 296;
          const int f4 = idx - r * 296;
          const float4 v = *(const float4*)(xc + (size_t)r * 4736 + 4 * f4);
          const float vv[4] = {v.x, v.y, v.z, v.w};
          const int f0 = 4 * f4;
          const int t0 = f0 / 37;
          const int k0 = f0 - 37 * t0;
#pragma unroll
          for (int e = 0; e < 4; e++) {
            int kk = k0 + e, tt = t0;
            if (kk >= 37) { kk -= 37; tt++; }
            xst[tt][r][kk] = (f16)vv[e];
          }
        }
      }
    }
    __syncthreads();  // xst staged (prev rec done -> ebunk free too)

    // ---- e-compute: 128 tile-jobs (32 t x 4 m) over 8 waves ----
#pragma unroll 1
    for (int jj = 0; jj < 16; jj++) {
      const int tl = 4 * w + (jj >> 2);
      const int m = jj & 3;
      const f16* px = &xst[tl][rho][0];
      const f16x8 xb0 = *(const f16x8*)(px + 8 * c);  // 16B aligned
      f16x8 xb1 = {};
      if (c == 0) {
#pragma unroll
        for (int i = 0; i < 5; i++) xb1[i] = px[32 + i];
      }
      f32x4 ea = MFMA16(w1a[m], xb0, ebias[m]);
      ea = MFMA16(w1b[m], xb1, ea);
      f16x4 pk;
#pragma unroll
      for (int r = 0; r < 4; r++) pk[r] = (f16)fmaxf(ea[r], 0.f);
      const int d0 = 16 * m + 4 * c;
      *(f16x4*)&ebunk[tl][m >> 1][rho | (((d0 >> 3) & 3) << 4)][d0 & 7] = pk;
    }
    __syncthreads();  // ebunk ready

    // ---- 32 recurrent steps (R8-proven body; e from LDS) ----
#pragma unroll 2
    for (int s = 0; s < 32; s++) {
      const int cur = s & 1;                 // chunk is 32 steps: parity safe
      const int tl = dir ? 31 - s : s;
      const f16x8 e0 = *(const f16x8*)&ebunk[tl][0][l][0];
      const f16x8 e1 = *(const f16x8*)&ebunk[tl][1][l][0];
      const f16x8 h0 = *(const f16x8*)&hbuf[cur][0][l][0];
      const f16x8 h1 = *(const f16x8*)&hbuf[cur][1][l][0];
#pragma unroll
      for (int q = 0; q < 2; q++) {
        f32x4 a = bias[q];
        a = MFMA16(aih[q][0], e0, a);
        a = MFMA16(aih[q][1], e1, a);
        a = MFMA16(ahh[q][0], h0, a);
        a = MFMA16(ahh[q][1], h1, a);
        // sig = rcp(1+exp2(y)), tanh = 2*rcp(1+exp2(y)) - 1 (pre-scaled)
        const float ig = rcp_(1.f + ex2_(a[0]));
        const float fg = rcp_(1.f + ex2_(a[1]));
        const float gg = 2.f * rcp_(1.f + ex2_(a[2])) - 1.f;
        const float og = rcp_(1.f + ex2_(a[3]));
        cst[q] = fg * cst[q] + ig * gg;
        const float th = 2.f * rcp_(1.f + ex2_(cst[q] * N2LOG2E)) - 1.f;
        const float h = og * th;
        hs[q] += h;  // fd accumulation (sum over t; reversal irrelevant)
        const int j = 8 * w + 4 * q + c;
        hbuf[cur ^ 1][j >> 5][rho | (((j >> 3) & 3) << 4)][j & 7] = (f16)h;
      }
      // lgkm-only barrier (proven R2/R8 pattern; nothing global in flight)
      asm volatile("s_waitcnt lgkmcnt(0)\n\ts_barrier" ::: "memory");
    }
    __syncthreads();  // chunk boundary: ebunk/xst reusable
  }

#pragma unroll
  for (int q = 0; q < 2; q++) {
    const int j = 8 * w + 4 * q + c;
    fd[(size_t)(bg * 16 + rho) * 128 + dir * 64 + j] = hs[q];
  }
}

// ---------------- Kernel 2: decoder (10 steps, constant input fd) -----------
__global__ __launch_bounds__(256) void decoder_k(
    const float* __restrict__ fd,
    const float* __restrict__ dwih, const float* __restrict__ dwhh,
    const float* __restrict__ dbih, const float* __restrict__ dbhh,
    const float* __restrict__ dlw, const float* __restrict__ dlb,
    const int* __restrict__ outlen_p, float* __restrict__ out) {
  const int b0 = blockIdx.x * 16;
  const int tid = threadIdx.x;
  const int w = tid >> 6, l = tid & 63;
  const int rho = l & 15, c = l >> 4;
  const int gate = rho & 3, uoff = rho >> 2;
  const int outlen = *outlen_p;

  __shared__ __align__(16) f16 hbuf[2][2][64][8];
  __shared__ float h32[64][16];
  __shared__ float ldslw[11 * 64];
  __shared__ float ldslb[16];
  __shared__ float lg[16][16];

  {
    int* hz = (int*)hbuf;
    for (int i = tid; i < (int)(sizeof(hbuf) / 4); i += 256) hz[i] = 0;
  }
  for (int i = tid; i < 704; i += 256) ldslw[i] = dlw[i];
  if (tid < 16) ldslb[tid] = (tid < 11) ? dlb[tid] : 0.f;

  f16x8 awhh[4][2];
  f32x4 acc0[4];  // bias + fd @ dec_wih^T : constant across steps
  {
    f16x8 bfd[4];
#pragma unroll
    for (int ks = 0; ks < 4; ks++) {
      const float* p = fd + (size_t)(b0 + rho) * 128 + ks * 32 + c * 8;
      f16x8 v;
#pragma unroll
      for (int i = 0; i < 8; i++) v[i] = (f16)p[i];
      bfd[ks] = v;
    }
#pragma unroll
    for (int q = 0; q < 4; q++) {
      const int m = 4 * w + q;
      const int n = gate * 64 + 4 * m + uoff;
      f32x4 a;
      const int j = 16 * w + 4 * q + c;
#pragma unroll
      for (int r = 0; r < 4; r++) a[r] = dbih[64 * r + j] + dbhh[64 * r + j];
#pragma unroll
      for (int ks = 0; ks < 4; ks++) {
        const float* p = dwih + n * 128 + ks * 32 + c * 8;
        f16x8 v;
#pragma unroll
        for (int i = 0; i < 8; i++) v[i] = (f16)p[i];
        a = MFMA16(v, bfd[ks], a);
      }
      acc0[q] = a;
#pragma unroll
      for (int ks = 0; ks < 2; ks++) {
        const float* p = dwhh + n * 64 + ks * 32 + c * 8;
        f16x8 v;
#pragma unroll
        for (int i = 0; i < 8; i++) v[i] = (f16)p[i];
        awhh[q][ks] = v;
      }
    }
  }
  float cst[4] = {0.f, 0.f, 0.f, 0.f};
  __syncthreads();

  for (int s = 0; s < outlen; s++) {
    const int cur = s & 1;
    f16x8 h0 = *(const f16x8*)&hbuf[cur][0][l][0];
    f16x8 h1 = *(const f16x8*)&hbuf[cur][1][l][0];
#pragma unroll
    for (int q = 0; q < 4; q++) {
      f32x4 a = acc0[q];
      a = MFMA16(awhh[q][0], h0, a);
      a = MFMA16(awhh[q][1], h1, a);
      const float ig = sigf(a[0]);
      const float fg = sigf(a[1]);
      const float gg = tanhf_fast(a[2]);
      const float og = sigf(a[3]);
      cst[q] = fg * cst[q] + ig * gg;
      const float h = og * tanhf_fast(cst[q]);
      const int j = 16 * w + 4 * q + c;
      hbuf[cur ^ 1][j >> 5][rho | (((j >> 3) & 3) << 4)][j & 7] = (f16)h;
      h32[j][rho] = h;
    }
    __syncthreads();
    const int b = tid >> 4, o = tid & 15;
    float logit = 0.f;
    if (o < 11) {
      logit = ldslb[o];
      for (int jj = 0; jj < 64; jj++) logit += h32[jj][b] * ldslw[o * 64 + jj];
      lg[b][o] = logit;
    }
    __syncthreads();
    if (o < 11) {
      float mx = lg[b][0];
      for (int k = 1; k < 11; k++) mx = fmaxf(mx, lg[b][k]);
      float sum = 0.f;
      for (int k = 0; k < 11; k++) sum += __expf(lg[b][k] - mx);
      out[(size_t)(b0 + b) * outlen * 11 + (size_t)s * 11 + o] =
          __expf(logit - mx) / sum;
    }
    __syncthreads();
  }
}

extern "C" void kernel_launch(void* const* d_in, const int* in_sizes, int n_in,
                              void* d_out, int out_size, void* d_ws, size_t ws_size,
                              hipStream_t stream) {
  const float* x = (const float*)d_in[0];
  const float* w1 = (const float*)d_in[1];
  const float* b1 = (const float*)d_in[2];
  const float* wih_f = (const float*)d_in[3];
  const float* whh_f = (const float*)d_in[4];
  const float* bih_f = (const float*)d_in[5];
  const float* bhh_f = (const float*)d_in[6];
  const float* wih_b = (const float*)d_in[7];
  const float* whh_b = (const float*)d_in[8];
  const float* bih_b = (const float*)d_in[9];
  const float* bhh_b = (const float*)d_in[10];
  // d_in[11..14]: attention weights — provably dead (softmax over size-1 axis)
  const float* dwih = (const float*)d_in[15];
  const float* dwhh = (const float*)d_in[16];
  const float* dbih = (const float*)d_in[17];
  const float* dbhh = (const float*)d_in[18];
  const float* dlw = (const float*)d_in[19];
  const float* dlb = (const float*)d_in[20];
  const int* outlen = (const int*)d_in[21];
  float* out = (float*)d_out;

  float* fd = (float*)d_ws;  // 1 MB

  hipLaunchKernelGGL(bilstm_fused_k, dim3(256), dim3(512), 0, stream,
                     x, w1, b1, wih_f, whh_f, bih_f, bhh_f,
                     wih_b, whh_b, bih_b, bhh_b, fd);
  hipLaunchKernelGGL(decoder_k, dim3(128), dim3(256), 0, stream,
                     fd, dwih, dwhh, dbih, dbhh, dlw, dlb, outlen, out);
}

// Round 13
// 117.120 us; speedup vs baseline: 5.2684x; 5.2684x over previous
//
#include <hip/hip_runtime.h>

// Model: enc linear(37->64)+relu -> BiLSTM(H=64, T=128, B=2048) -> (degenerate
// attention == sum over T) -> 10-step decoder LSTM with constant input -> softmax(11).
//
// Exploits: attention weights are all-ones (softmax over a size-1 axis), so
// fd[b] = sum_t concat(hf,hb)[b,t,:] and att1/att2 are dead. fd@dec_wih.T is
// hoisted out of the decoder loop.
//
// R13: fusion abandoned (5 failures). R8 structure + one chain optimization in
// bilstm: the input-side MFMAs (bias + ih*e, h-independent) for step t+1 are
// computed AFTER the h-write of step t, before the barrier -- off the critical
// path, filling the pre-barrier stall. Post-barrier chain: h-read -> 2-deep hh
// MFMA -> pointwise (was 4-deep). Summation order unchanged (bit-identical).
// enc = R9's direct-store variant; decoder unchanged.

typedef _Float16 f16;
typedef f16 f16x8 __attribute__((ext_vector_type(8)));
typedef f16 f16x4 __attribute__((ext_vector_type(4)));
typedef float f32x4 __attribute__((ext_vector_type(4)));

#define MFMA16(a, b, c) __builtin_amdgcn_mfma_f32_16x16x32_f16(a, b, c, 0, 0, 0)

// gate scales folded into weights: i,f,o -> -log2e ; g -> -2*log2e
// then sig = rcp(1+exp2(y)), tanh = 2*rcp(1+exp2(y)) - 1.
#define NLOG2E  -1.4426950408889634f
#define N2LOG2E -2.8853900817779268f

__device__ __forceinline__ float rcp_(float x) { return __builtin_amdgcn_rcpf(x); }
__device__ __forceinline__ float ex2_(float x) { return __builtin_amdgcn_exp2f(x); }
__device__ __forceinline__ float sigf(float x) { return 1.f / (1.f + __expf(-x)); }
__device__ __forceinline__ float tanhf_fast(float x) {
  float e = __expf(2.f * x);
  return 1.f - 2.f / (e + 1.f);
}

// e-fragment tensor layout (f16, 32 MB in d_ws):
//   addr16B = ((t*128 + bgroup)*2 + ksub)*64 + slot ; slot = (b&15) | (((k>>3)&3)<<4)
//   within-slot element i = k&7 ; k = ksub*32 + 8*(slot>>4) + i
// == the 16x16x32 MFMA B-fragment for B[k][b] = e[b][k].

// ---------------- Kernel A: e = relu(x @ W1^T + b1), direct-store -----------
// Block: 16 batch rows x 16 timesteps; 256 thr, 4 independent waves (no LDS,
// no barriers). Lane (rho,c) loads x[row=rho][t][8c..8c+7] direct from global;
// C/D f16x4 results stored straight to efrag (8B stores, L2 merges pairs).
__global__ __launch_bounds__(256) void enc_linear_k(
    const float* __restrict__ x, const float* __restrict__ w1,
    const float* __restrict__ b1, f16* __restrict__ efrag) {
  const int bg = blockIdx.x;   // 0..127
  const int tc = blockIdx.y;   // 0..7  (16 t each)
  const int tid = threadIdx.x;
  const int w = tid >> 6, l = tid & 63;
  const int rho = l & 15, c = l >> 4;

  // ---- W1 A-frags (4 m-tiles; K padded 37 -> 64 with zeros) ----
  f16x8 w1a[4], w1b[4];
  f32x4 ebias[4];
#pragma unroll
  for (int m = 0; m < 4; m++) {
    const float* pw = w1 + (16 * m + rho) * 37;
    f16x8 v0, v1;
#pragma unroll
    for (int i = 0; i < 8; i++) {
      v0[i] = (f16)pw[8 * c + i];
      v1[i] = (f16)((c == 0 && i < 5) ? pw[32 + i] : 0.f);
    }
    w1a[m] = v0;
    w1b[m] = v1;
#pragma unroll
    for (int r = 0; r < 4; r++) ebias[m][r] = b1[16 * m + 4 * c + r];
  }

  const float* xrow = x + (size_t)(bg * 16 + rho) * 4736 + (size_t)(tc * 16) * 37;

  // ---- 4 t per wave: direct loads -> B-frag -> 8 MFMA -> direct stores ----
#pragma unroll
  for (int ti = 0; ti < 4; ti++) {
    const int tl = 4 * w + ti;
    const float* px = xrow + tl * 37;
    f16x8 xb0, xb1 = {};
#pragma unroll
    for (int i = 0; i < 8; i++) xb0[i] = (f16)px[8 * c + i];
    if (c == 0) {
#pragma unroll
      for (int i = 0; i < 5; i++) xb1[i] = (f16)px[32 + i];
    }
    const size_t tbase = ((size_t)((tc * 16 + tl) * 128 + bg)) * 2;
#pragma unroll
    for (int m = 0; m < 4; m++) {
      f32x4 ea = MFMA16(w1a[m], xb0, ebias[m]);
      ea = MFMA16(w1b[m], xb1, ea);
      f16x4 pk;
#pragma unroll
      for (int r = 0; r < 4; r++) pk[r] = (f16)fmaxf(ea[r], 0.f);
      const int d0 = 16 * m + 4 * c;
      const int slot = rho | (((d0 >> 3) & 3) << 4);
      *(f16x4*)&efrag[((tbase + (m >> 1)) * 64 + slot) * 8 + (d0 & 7)] = pk;
    }
  }
}

// ---------------- Kernel B: BiLSTM, fd accumulation -------------------------
// 8 waves/block (512 thr): wave w owns m-tiles {2w, 2w+1}; gate-interleaved row
// permutation puts all 4 gates of cell (b, j) into one lane's 4 acc regs.
// R13: ih-MFMAs for step t+1 computed after the h-write of step t (pre-barrier
// stall shadow); post-barrier chain is h-read -> 2-deep hh MFMA -> pointwise.
__global__ __launch_bounds__(512, 2) void bilstm_k(
    const f16* __restrict__ efrag,
    const float* __restrict__ wih_f, const float* __restrict__ whh_f,
    const float* __restrict__ bih_f, const float* __restrict__ bhh_f,
    const float* __restrict__ wih_b, const float* __restrict__ whh_b,
    const float* __restrict__ bih_b, const float* __restrict__ bhh_b,
    float* __restrict__ fd) {
  const int bid = blockIdx.x;
  const int dir = bid >> 7;
  const int bg = bid & 127;
  const int tid = threadIdx.x;
  const int w = tid >> 6, l = tid & 63;      // w in [0,8)
  const int rho = l & 15, c = l >> 4;
  const int gate = rho & 3, uoff = rho >> 2;

  const float* wih = dir ? wih_b : wih_f;
  const float* whh = dir ? whh_b : whh_f;
  const float* bih = dir ? bih_b : bih_f;
  const float* bhh = dir ? bhh_b : bhh_f;

  __shared__ __align__(16) f16 hbuf[2][2][64][8];
  {
    int* hz = (int*)hbuf;
    for (int i = tid; i < (int)(sizeof(hbuf) / 4); i += 512) hz[i] = 0;
  }

  // Row scale by gate (exp2 folding): rows of gate g scaled by SG[g].
  const float sA = (gate == 2) ? N2LOG2E : NLOG2E;

  // Permuted-weight A-fragments, registers for all 128 steps.
  // m-tile m = 2w+q; fragment row rho -> original W row n = 64*gate + 4m + uoff.
  f16x8 aih[2][2], ahh[2][2];
#pragma unroll
  for (int q = 0; q < 2; q++) {
    const int m = 2 * w + q;
    const int n = gate * 64 + 4 * m + uoff;
#pragma unroll
    for (int ks = 0; ks < 2; ks++) {
      const float* p1 = wih + n * 64 + ks * 32 + c * 8;
      const float* p2 = whh + n * 64 + ks * 32 + c * 8;
      f16x8 v1, v2;
#pragma unroll
      for (int i = 0; i < 8; i++) {
        v1[i] = (f16)(p1[i] * sA);
        v2[i] = (f16)(p2[i] * sA);
      }
      aih[q][ks] = v1;
      ahh[q][ks] = v2;
    }
  }
  // Per-lane bias: acc reg r of m-tile q is gate r of unit j = 8w + 4q + c.
  f32x4 bias[2];
#pragma unroll
  for (int q = 0; q < 2; q++) {
    const int j = 8 * w + 4 * q + c;
#pragma unroll
    for (int r = 0; r < 4; r++) {
      const float sr = (r == 2) ? N2LOG2E : NLOG2E;
      bias[q][r] = (bih[64 * r + j] + bhh[64 * r + j]) * sr;
    }
  }

  const f16x8* eb = (const f16x8*)efrag;
#define EIDX(t) (((size_t)(((dir ? 127 - (t) : (t)) * 128) + bg) * 2) * 64 + l)
  // 3-deep e prefetch pipeline: ~1600cy of cover for L2/HBM misses.
  f16x8 ec0 = eb[EIDX(0)], ec1 = eb[EIDX(0) + 64];
  f16x8 e10 = eb[EIDX(1)], e11 = eb[EIDX(1) + 64];
  f16x8 e20 = eb[EIDX(2)], e21 = eb[EIDX(2) + 64];

  float cst[2] = {0.f, 0.f};
  float hs[2] = {0.f, 0.f};

  // prologue: ihacc for step 0 (bias + ih0*e0 + ih1*e1; h-independent)
  f32x4 ihacc[2];
#pragma unroll
  for (int q = 0; q < 2; q++) {
    f32x4 a = bias[q];
    a = MFMA16(aih[q][0], ec0, a);
    a = MFMA16(aih[q][1], ec1, a);
    ihacc[q] = a;
  }

  __syncthreads();  // hbuf zeros visible

#pragma unroll 4
  for (int t = 0; t < 128; t++) {
    const int cur = t & 1;
    // issue prefetch for t+3 (clamped; redundant loads at tail are harmless)
    const int t3 = (t + 3 < 128) ? t + 3 : 127;
    const f16x8 ld0 = eb[EIDX(t3)];
    const f16x8 ld1 = eb[EIDX(t3) + 64];

    // ---- h-dependent part: 2-deep hh chain onto precomputed ihacc ----
    f16x8 h0 = *(const f16x8*)&hbuf[cur][0][l][0];
    f16x8 h1 = *(const f16x8*)&hbuf[cur][1][l][0];
#pragma unroll
    for (int q = 0; q < 2; q++) {
      f32x4 a = ihacc[q];
      a = MFMA16(ahh[q][0], h0, a);
      a = MFMA16(ahh[q][1], h1, a);
      // pointwise: sig = rcp(1+exp2(y)), tanh = 2*rcp(1+exp2(y)) - 1
      const float ig = rcp_(1.f + ex2_(a[0]));
      const float fg = rcp_(1.f + ex2_(a[1]));
      const float gg = 2.f * rcp_(1.f + ex2_(a[2])) - 1.f;
      const float og = rcp_(1.f + ex2_(a[3]));
      cst[q] = fg * cst[q] + ig * gg;
      const float th = 2.f * rcp_(1.f + ex2_(cst[q] * N2LOG2E)) - 1.f;
      const float h = og * th;
      hs[q] += h;  // fd accumulation (sum over t; reversal irrelevant)
      const int j = 8 * w + 4 * q + c;
      hbuf[cur ^ 1][j >> 5][rho | (((j >> 3) & 3) << 4)][j & 7] = (f16)h;
    }
    // rotate prefetch pipeline (unroll 4 renames these away)
    ec0 = e10; ec1 = e11;
    e10 = e20; e11 = e21;
    e20 = ld0; e21 = ld1;
    // ---- stall-filler: ih MFMAs for step t+1 (h-independent) ----
#pragma unroll
    for (int q = 0; q < 2; q++) {
      f32x4 a = bias[q];
      a = MFMA16(aih[q][0], ec0, a);
      a = MFMA16(aih[q][1], ec1, a);
      ihacc[q] = a;
    }
    // lgkm-only barrier: LDS h exchange must drain; global e prefetch
    // (vmcnt) stays in flight across the step boundary.
    asm volatile("s_waitcnt lgkmcnt(0)\n\ts_barrier" ::: "memory");
  }
#undef EIDX
#pragma unroll
  for (int q = 0; q < 2; q++) {
    const int j = 8 * w + 4 * q + c;
    fd[(size_t)(bg * 16 + rho) * 128 + dir * 64 + j] = hs[q];
  }
}

// ---------------- Kernel C: decoder (10 steps, constant input fd) -----------
__global__ __launch_bounds__(256) void decoder_k(
    const float* __restrict__ fd,
    const float* __restrict__ dwih, const float* __restrict__ dwhh,
    const float* __restrict__ dbih, const float* __restrict__ dbhh,
    const float* __restrict__ dlw, const float* __restrict__ dlb,
    const int* __restrict__ outlen_p, float* __restrict__ out) {
  const int b0 = blockIdx.x * 16;
  const int tid = threadIdx.x;
  const int w = tid >> 6, l = tid & 63;
  const int rho = l & 15, c = l >> 4;
  const int gate = rho & 3, uoff = rho >> 2;
  const int outlen = *outlen_p;

  __shared__ __align__(16) f16 hbuf[2][2][64][8];
  __shared__ float h32[64][16];
  __shared__ float ldslw[11 * 64];
  __shared__ float ldslb[16];
  __shared__ float lg[16][16];

  {
    int* hz = (int*)hbuf;
    for (int i = tid; i < (int)(sizeof(hbuf) / 4); i += 256) hz[i] = 0;
  }
  for (int i = tid; i < 704; i += 256) ldslw[i] = dlw[i];
  if (tid < 16) ldslb[tid] = (tid < 11) ? dlb[tid] : 0.f;

  f16x8 awhh[4][2];
  f32x4 acc0[4];  // bias + fd @ dec_wih^T : constant across steps
  {
    f16x8 bfd[4];
#pragma unroll
    for (int ks = 0; ks < 4; ks++) {
      const float* p = fd + (size_t)(b0 + rho) * 128 + ks * 32 + c * 8;
      f16x8 v;
#pragma unroll
      for (int i = 0; i < 8; i++) v[i] = (f16)p[i];
      bfd[ks] = v;
    }
#pragma unroll
    for (int q = 0; q < 4; q++) {
      const int m = 4 * w + q;
      const int n = gate * 64 + 4 * m + uoff;
      f32x4 a;
      const int j = 16 * w + 4 * q + c;
#pragma unroll
      for (int r = 0; r < 4; r++) a[r] = dbih[64 * r + j] + dbhh[64 * r + j];
#pragma unroll
      for (int ks = 0; ks < 4; ks++) {
        const float* p = dwih + n * 128 + ks * 32 + c * 8;
        f16x8 v;
#pragma unroll
        for (int i = 0; i < 8; i++) v[i] = (f16)p[i];
        a = MFMA16(v, bfd[ks], a);
      }
      acc0[q] = a;
#pragma unroll
      for (int ks = 0; ks < 2; ks++) {
        const float* p = dwhh + n * 64 + ks * 32 + c * 8;
        f16x8 v;
#pragma unroll
        for (int i = 0; i < 8; i++) v[i] = (f16)p[i];
        awhh[q][ks] = v;
      }
    }
  }
  float cst[4] = {0.f, 0.f, 0.f, 0.f};
  __syncthreads();

  for (int s = 0; s < outlen; s++) {
    const int cur = s & 1;
    f16x8 h0 = *(const f16x8*)&hbuf[cur][0][l][0];
    f16x8 h1 = *(const f16x8*)&hbuf[cur][1][l][0];
#pragma unroll
    for (int q = 0; q < 4; q++) {
      f32x4 a = acc0[q];
      a = MFMA16(awhh[q][0], h0, a);
      a = MFMA16(awhh[q][1], h1, a);
      const float ig = sigf(a[0]);
      const float fg = sigf(a[1]);
      const float gg = tanhf_fast(a[2]);
      const float og = sigf(a[3]);
      cst[q] = fg * cst[q] + ig * gg;
      const float h = og * tanhf_fast(cst[q]);
      const int j = 16 * w + 4 * q + c;
      hbuf[cur ^ 1][j >> 5][rho | (((j >> 3) & 3) << 4)][j & 7] = (f16)h;
      h32[j][rho] = h;
    }
    __syncthreads();
    const int b = tid >> 4, o = tid & 15;
    float logit = 0.f;
    if (o < 11) {
      logit = ldslb[o];
      for (int jj = 0; jj < 64; jj++) logit += h32[jj][b] * ldslw[o * 64 + jj];
      lg[b][o] = logit;
    }
    __syncthreads();
    if (o < 11) {
      float mx = lg[b][0];
      for (int k = 1; k < 11; k++) mx = fmaxf(mx, lg[b][k]);
      float sum = 0.f;
      for (int k = 0; k < 11; k++) sum += __expf(lg[b][k] - mx);
      out[(size_t)(b0 + b) * outlen * 11 + (size_t)s * 11 + o] =
          __expf(logit - mx) / sum;
    }
    __syncthreads();
  }
}

extern "C" void kernel_launch(void* const* d_in, const int* in_sizes, int n_in,
                              void* d_out, int out_size, void* d_ws, size_t ws_size,
                              hipStream_t stream) {
  const float* x = (const float*)d_in[0];
  const float* w1 = (const float*)d_in[1];
  const float* b1 = (const float*)d_in[2];
  const float* wih_f = (const float*)d_in[3];
  const float* whh_f = (const float*)d_in[4];
  const float* bih_f = (const float*)d_in[5];
  const float* bhh_f = (const float*)d_in[6];
  const float* wih_b = (const float*)d_in[7];
  const float* whh_b = (const float*)d_in[8];
  const float* bih_b = (const float*)d_in[9];
  const float* bhh_b = (const float*)d_in[10];
  // d_in[11..14]: attention weights — provably dead (softmax over size-1 axis)
  const float* dwih = (const float*)d_in[15];
  const float* dwhh = (const float*)d_in[16];
  const float* dbih = (const float*)d_in[17];
  const float* dbhh = (const float*)d_in[18];
  const float* dlw = (const float*)d_in[19];
  const float* dlb = (const float*)d_in[20];
  const int* outlen = (const int*)d_in[21];
  float* out = (float*)d_out;

  f16* efrag = (f16*)d_ws;                              // 32 MB
  float* fd = (float*)((char*)d_ws + (size_t)33554432); // 1 MB

  hipLaunchKernelGGL(enc_linear_k, dim3(128, 8), dim3(256), 0, stream,
                     x, w1, b1, efrag);
  hipLaunchKernelGGL(bilstm_k, dim3(256), dim3(512), 0, stream,
                     efrag, wih_f, whh_f, bih_f, bhh_f,
                     wih_b, whh_b, bih_b, bhh_b, fd);
  hipLaunchKernelGGL(decoder_k, dim3(128), dim3(256), 0, stream,
                     fd, dwih, dwhh, dbih, dbhh, dlw, dlb, outlen, out);
}